// Round 6
// baseline (342.668 us; speedup 1.0000x reference)
//
#include <hip/hip_runtime.h>
#include <hip/hip_bf16.h>
#include <stdint.h>

// Problem constants (Attention_21552145891894): B=64, S=1024, DEC=ENC=ATTN=1024
#define NB 64
#define NS 1024
#define NE 1024   // ENC (= K of big GEMM)
#define NA 1024   // ATTN (= N of big GEMM)
#define NF 2048   // DEC+ENC (W_attn row length)
#define LDP 144   // padded LDS row stride (fallback reg-staged kernel only)
#define SLOT 49152  // 8-phase kernel: A(32KB)+B(16KB) per K-tile slot

typedef __attribute__((ext_vector_type(8))) short   short8;
typedef __attribute__((ext_vector_type(4))) short   short4v;
typedef __attribute__((ext_vector_type(4))) float   f32x4;
typedef __attribute__((ext_vector_type(8))) __bf16  bf16x8;

__device__ __forceinline__ unsigned short f2bf(float x) {
  union { float f; unsigned u; } v; v.f = x;
  unsigned r = v.u + 0x7fffu + ((v.u >> 16) & 1u);   // RNE
  return (unsigned short)(r >> 16);
}
__device__ __forceinline__ float bf2f(unsigned short h) {
  union { unsigned u; float f; } v; v.u = ((unsigned)h) << 16;
  return v.f;
}
__device__ __forceinline__ float tanh_fast(float x) {
  float e = __expf(2.0f * x);                        // overflow -> inf -> 1; underflow -> -1
  return 1.0f - __fdividef(2.0f, e + 1.0f);
}
__device__ __forceinline__ short8 pack8(float4 a, float4 b) {
  short8 h;
  h[0]=(short)f2bf(a.x); h[1]=(short)f2bf(a.y); h[2]=(short)f2bf(a.z); h[3]=(short)f2bf(a.w);
  h[4]=(short)f2bf(b.x); h[5]=(short)f2bf(b.y); h[6]=(short)f2bf(b.z); h[7]=(short)f2bf(b.w);
  return h;
}
__device__ __forceinline__ void gload_lds16(const void* g, void* l) {
  // HW: LDS dest is wave-uniform base + lane*16; size must be literal 16 (m97/m104)
  __builtin_amdgcn_global_load_lds((const __attribute__((address_space(1))) void*)g,
                                   (__attribute__((address_space(3))) void*)l, 16, 0, 0);
}

// ---------------- zero scratch (scores + ctx), deterministic each call ----------------
__global__ __launch_bounds__(256) void k_zero(float4* __restrict__ p, int n4) {
  int i = blockIdx.x * 256 + threadIdx.x;
  if (i < n4) { float4 z; z.x = z.y = z.z = z.w = 0.f; p[i] = z; }
}

// ---------------- enc f32 -> bf16 (ws) ----------------
__global__ __launch_bounds__(256) void k_conv_enc(const float4* __restrict__ src,
                                                  short8* __restrict__ dst, int n8) {
  int i = blockIdx.x * 256 + threadIdx.x;
  const int stride = gridDim.x * 256;
  for (; i < n8; i += stride) {
    float4 a = src[2 * i], b = src[2 * i + 1];
    dst[i] = pack8(a, b);
  }
}

// ---------------- W_enc (= W_attn[:,1024:2048]) f32 -> bf16 [1024][1024] ----------------
__global__ __launch_bounds__(256) void k_conv_w(const float* __restrict__ W, short8* __restrict__ dst) {
  const int id = blockIdx.x * 256 + threadIdx.x;   // 131072 total
  const int a = id >> 7, ku = id & 127;
  const float* s = W + (size_t)a * NF + 1024 + ku * 8;
  float4 x = *(const float4*)s;
  float4 y = *(const float4*)(s + 4);
  dst[id] = pack8(x, y);
}

// ---------------- u[b,a] = hidden[b] . W_attn[a,0:1024] + b_attn[a]  (fp32 exact) ----------------
__global__ __launch_bounds__(256) void k_u(const float* __restrict__ hidden,
                                           const float* __restrict__ W,
                                           const float* __restrict__ bias,
                                           float* __restrict__ u) {
  const int l = threadIdx.x & 63;
  const int w = threadIdx.x >> 6;
  const int a = (blockIdx.x >> 1) * 4 + w;         // grid 512 -> a in [0,1024)
  const int bh = blockIdx.x & 1;
  const float* wrow = W + (size_t)a * NF;          // dec half: cols 0..1023
  float4 wv[4];
  #pragma unroll
  for (int i = 0; i < 4; ++i) wv[i] = *(const float4*)(wrow + l * 4 + i * 256);
  const float ba = bias[a];
  for (int b = bh * 32; b < bh * 32 + 32; ++b) {
    const float* hrow = hidden + b * 1024;
    float s = 0.f;
    #pragma unroll
    for (int i = 0; i < 4; ++i) {
      float4 hv = *(const float4*)(hrow + l * 4 + i * 256);
      s += wv[i].x * hv.x + wv[i].y * hv.y + wv[i].z * hv.z + wv[i].w * hv.w;
    }
    #pragma unroll
    for (int m = 1; m < 64; m <<= 1) s += __shfl_xor(s, m);
    if (l == 0) u[b * NA + a] = s + ba;
  }
}

// ======== main fused GEMM (tier0), deep-pipelined 3-slot ring ========
// BM=256, BN=128, BK=64; 8 waves (4M x 2N), 64x64 output/wave, 16x16x32 bf16 MFMA.
// LDS: 3 slots of {A[256][64]bf16 (32KB) + B[128][64]bf16 (16KB)}; tile t lives in
// slot t%3. While computing tile t (2 phases x 16 MFMA), stage tile t+2 into slot
// (t+2)%3 (A halves at ph0: 4 loads/thread; B at ph1: 2 loads/thread). Counted
// vmcnt at ph0 only: youngest 10 loads = tile t-1's 6 + own 4 -> vmcnt(10)
// certifies tile t (uniform for t=0..13 incl. prologue; t=14 -> 6, t=15 -> 0).
// Raw s_barrier (asm, memory clobber) - no compiler vmcnt(0) drain. k-unit XOR
// swizzle both-sides (pre-swizzled gload source, XOR'd ds_read) - verified r5.
__global__ __launch_bounds__(512, 2) void k_main8(const unsigned short* __restrict__ Ab,
                                                  const unsigned short* __restrict__ Bb,
                                                  const float* __restrict__ u_,
                                                  const float* __restrict__ v_,
                                                  float* __restrict__ scores) {
  __shared__ __align__(16) char smem[3 * SLOT];

  const int tid = threadIdx.x;
  const int l = tid & 63;
  const int w = tid >> 6;                   // 0..7
  const int wr = w >> 1, wc = w & 1;        // 4M x 2N wave grid
  // XCD-chunked remap (bijective: 2048 = 8 xcd * 8 ct * 32 rt-chunk): the 8
  // col-tiles of one row-panel are consecutive on one XCD -> A-panel L2 reuse.
  const int d = blockIdx.x;
  const int rt = (d & 7) * 32 + (d >> 6);   // row tile [0,256)
  const int ct = (d >> 3) & 7;              // col tile [0,8)
  const int b = rt >> 2;                    // batch (256-row tiles never straddle)
  const int lh = l >> 4, l15 = l & 15, l7 = l & 7;

  // staging lane mapping: row offset w*8 + (l>>3), k-unit l&7, pre-swizzled source
  const int sr  = w * 8 + (l >> 3);         // 0..63
  const int ssk = (l7 ^ (l >> 3)) * 8;      // inverse-swizzled k offset (bf16)
  const unsigned short* aS = Ab + (size_t)(rt * 256 + sr) * NE + ssk;
  const unsigned short* bS = Bb + (size_t)(ct * 128 + sr) * NE + ssk;
  const int wdst = w * 8 * 128;             // wave-uniform LDS dest offset

  // stage A-tile (4 issues: h*128 + j*64 rows) / B-tile (2 issues) of K-tile t
  #define STG_A(slotp, t) do { \
    gload_lds16(aS + (size_t)  0 * NE + (t) * 64, (slotp) +    0 + wdst); \
    gload_lds16(aS + (size_t) 64 * NE + (t) * 64, (slotp) + 64*128 + wdst); \
    gload_lds16(aS + (size_t)128 * NE + (t) * 64, (slotp) +128*128 + wdst); \
    gload_lds16(aS + (size_t)192 * NE + (t) * 64, (slotp) +192*128 + wdst); } while (0)
  #define STG_B(slotp, t) do { \
    gload_lds16(bS + (size_t)  0 * NE + (t) * 64, (slotp) + 32768 +    0 + wdst); \
    gload_lds16(bS + (size_t) 64 * NE + (t) * 64, (slotp) + 32768 + 64*128 + wdst); } while (0)

  f32x4 acc[4][4] = {};
  bf16x8 a[4][2], bbf[2][2];

  char* s0 = smem;
  char* s1 = smem + SLOT;
  char* s2 = smem + 2 * SLOT;

  // prologue: tiles 0 and 1 (6 loads each, A then B)
  STG_A(s0, 0); STG_B(s0, 0);
  STG_A(s1, 1); STG_B(s1, 1);

  char* cur = s0; char* nxt = s1; char* st2 = s2;

  for (int t = 0; t < 16; ++t) {
    // ---- phase 0: stage A(t+2); certify tile t; compute cols-half 0 ----
    if (t < 14) STG_A(st2, t + 2);
    if (t < 14)      asm volatile("s_waitcnt vmcnt(10)" ::: "memory");
    else if (t == 14) asm volatile("s_waitcnt vmcnt(6)" ::: "memory");
    else              asm volatile("s_waitcnt vmcnt(0)" ::: "memory");
    asm volatile("s_barrier" ::: "memory");

    #pragma unroll
    for (int rf = 0; rf < 4; ++rf)
      #pragma unroll
      for (int kh = 0; kh < 2; ++kh)
        a[rf][kh] = *(const bf16x8*)(cur + (wr * 64 + rf * 16 + l15) * 128
                                         + (((kh * 4 + lh) ^ l7) << 4));
    #pragma unroll
    for (int g = 0; g < 2; ++g)
      #pragma unroll
      for (int kh = 0; kh < 2; ++kh)
        bbf[g][kh] = *(const bf16x8*)(cur + 32768 + (wc * 64 + g * 16 + l15) * 128
                                          + (((kh * 4 + lh) ^ l7) << 4));
    __builtin_amdgcn_s_setprio(1);
    #pragma unroll
    for (int rf = 0; rf < 4; ++rf)
      #pragma unroll
      for (int g = 0; g < 2; ++g)
        #pragma unroll
        for (int kh = 0; kh < 2; ++kh)
          acc[rf][g] = __builtin_amdgcn_mfma_f32_16x16x32_bf16(a[rf][kh], bbf[g][kh], acc[rf][g], 0, 0, 0);
    __builtin_amdgcn_s_setprio(0);
    asm volatile("s_barrier" ::: "memory");

    // ---- phase 1: stage B(t+2); compute cols-half 1 (A regs reused) ----
    if (t < 14) STG_B(st2, t + 2);
    #pragma unroll
    for (int g = 0; g < 2; ++g)
      #pragma unroll
      for (int kh = 0; kh < 2; ++kh)
        bbf[g][kh] = *(const bf16x8*)(cur + 32768 + (wc * 64 + (2 + g) * 16 + l15) * 128
                                          + (((kh * 4 + lh) ^ l7) << 4));
    __builtin_amdgcn_s_setprio(1);
    #pragma unroll
    for (int rf = 0; rf < 4; ++rf)
      #pragma unroll
      for (int g = 0; g < 2; ++g)
        #pragma unroll
        for (int kh = 0; kh < 2; ++kh)
          acc[rf][2 + g] = __builtin_amdgcn_mfma_f32_16x16x32_bf16(a[rf][kh], bbf[g][kh], acc[rf][2 + g], 0, 0, 0);
    __builtin_amdgcn_s_setprio(0);
    asm volatile("s_barrier" ::: "memory");

    // rotate ring: cur <- nxt <- st2 <- cur
    char* tmp = cur; cur = nxt; nxt = st2; st2 = tmp;
  }

  // ---- epilogue: D frag col=l&15, row=(l>>4)*4+reg (m89-verified) ----
  const int colb = ct * 128 + wc * 64 + l15;
  float uv[4], vv[4];
  #pragma unroll
  for (int cf = 0; cf < 4; ++cf) {
    const int c = colb + cf * 16;
    uv[cf] = u_[b * NA + c];
    vv[cf] = v_[c];
  }
  #pragma unroll
  for (int rf = 0; rf < 4; ++rf) {
    #pragma unroll
    for (int reg = 0; reg < 4; ++reg) {
      float sacc = 0.f;
      #pragma unroll
      for (int cf = 0; cf < 4; ++cf)
        sacc += tanh_fast(acc[rf][cf][reg] + uv[cf]) * vv[cf];
      sacc += __shfl_xor(sacc, 1);
      sacc += __shfl_xor(sacc, 2);
      sacc += __shfl_xor(sacc, 4);
      sacc += __shfl_xor(sacc, 8);
      if (l15 == 0) {
        const int m = rt * 256 + wr * 64 + rf * 16 + lh * 4 + reg;
        atomicAdd(&scores[m], sacc);         // 16 partials per row (8 ct x 2 wc)
      }
    }
  }
  #undef STG_A
  #undef STG_B
}

// ======== fallback (small ws): reg-staged padded-LDS version (round-3-verified) ========
template <int ACONV, int BCONV>
__global__ __launch_bounds__(256) void k_main_rs(const void* __restrict__ Asrc,
                                                 const void* __restrict__ Bsrc,
                                                 const float* __restrict__ u_,
                                                 const float* __restrict__ v_,
                                                 float* __restrict__ scores) {
  __shared__ __align__(16) char smemf[2 * 128 * LDP];
  char* As = smemf;
  char* Bs = smemf + 128 * LDP;
  const int tid = threadIdx.x;
  const int l = tid & 63;
  const int w = tid >> 6;
  const int wr = w >> 1, wc = w & 1;
  const int d = blockIdx.x;
  const int rt = (d & 7) * 64 + (d >> 6);
  const int ct = (d >> 3) & 7;
  const int b = rt >> 3;
  const int l7 = l & 7, lh = l >> 4, l15 = l & 15;
  const int srow = w * 8 + (l >> 3);
  f32x4 acc[4][4] = {};
  for (int kt = 0; kt < 16; ++kt) {
    const int k0 = kt * 64;
    __syncthreads();
    #pragma unroll
    for (int r = 0; r < 4; ++r) {
      const int row = r * 32 + srow;
      short8 val;
      if constexpr (ACONV) {
        const float* s = (const float*)Asrc + (size_t)(rt * 128 + row) * NE + k0 + l7 * 8;
        val = pack8(*(const float4*)s, *(const float4*)(s + 4));
      } else {
        val = *(const short8*)((const unsigned short*)Asrc + (size_t)(rt * 128 + row) * NE + k0 + l7 * 8);
      }
      *(short8*)(As + row * LDP + l7 * 16) = val;
    }
    #pragma unroll
    for (int r = 0; r < 4; ++r) {
      const int row = r * 32 + srow;
      short8 val;
      if constexpr (BCONV) {
        const float* s = (const float*)Bsrc + (size_t)(ct * 128 + row) * NF + 1024 + k0 + l7 * 8;
        val = pack8(*(const float4*)s, *(const float4*)(s + 4));
      } else {
        val = *(const short8*)((const unsigned short*)Bsrc + (size_t)(ct * 128 + row) * NE + k0 + l7 * 8);
      }
      *(short8*)(Bs + row * LDP + l7 * 16) = val;
    }
    __syncthreads();
    #pragma unroll
    for (int ks = 0; ks < 2; ++ks) {
      bf16x8 af[4], bfr[4];
      const int ku = (ks * 4 + lh) * 16;
      #pragma unroll
      for (int f = 0; f < 4; ++f) {
        af[f]  = *(const bf16x8*)(As + (wr * 64 + f * 16 + l15) * LDP + ku);
        bfr[f] = *(const bf16x8*)(Bs + (wc * 64 + f * 16 + l15) * LDP + ku);
      }
      #pragma unroll
      for (int i = 0; i < 4; ++i)
        #pragma unroll
        for (int jj = 0; jj < 4; ++jj)
          acc[i][jj] = __builtin_amdgcn_mfma_f32_16x16x32_bf16(af[i], bfr[jj], acc[i][jj], 0, 0, 0);
    }
  }
  const int colb = ct * 128 + wc * 64 + l15;
  float uv[4], vv[4];
  #pragma unroll
  for (int jj = 0; jj < 4; ++jj) {
    const int c = colb + jj * 16;
    uv[jj] = u_[b * NA + c];
    vv[jj] = v_[c];
  }
  #pragma unroll
  for (int i = 0; i < 4; ++i) {
    #pragma unroll
    for (int reg = 0; reg < 4; ++reg) {
      float sacc = 0.f;
      #pragma unroll
      for (int jj = 0; jj < 4; ++jj)
        sacc += tanh_fast(acc[i][jj][reg] + uv[jj]) * vv[jj];
      sacc += __shfl_xor(sacc, 1);
      sacc += __shfl_xor(sacc, 2);
      sacc += __shfl_xor(sacc, 4);
      sacc += __shfl_xor(sacc, 8);
      if (l15 == 0) {
        const int m = rt * 128 + wr * 64 + i * 16 + lh * 4 + reg;
        atomicAdd(&scores[m], sacc);
      }
    }
  }
}

// ---------------- softmax over S per batch (in-place) ----------------
__global__ __launch_bounds__(256) void k_softmax(float* __restrict__ sc) {
  const int b = blockIdx.x, t = threadIdx.x;
  float4 x = *(float4*)(sc + b * NS + t * 4);
  float mx = fmaxf(fmaxf(x.x, x.y), fmaxf(x.z, x.w));
  #pragma unroll
  for (int m = 1; m < 64; m <<= 1) mx = fmaxf(mx, __shfl_xor(mx, m));
  __shared__ float rmax[4], rsum[4];
  if ((t & 63) == 0) rmax[t >> 6] = mx;
  __syncthreads();
  mx = fmaxf(fmaxf(rmax[0], rmax[1]), fmaxf(rmax[2], rmax[3]));
  float e0 = __expf(x.x - mx), e1 = __expf(x.y - mx);
  float e2 = __expf(x.z - mx), e3 = __expf(x.w - mx);
  float sm = e0 + e1 + e2 + e3;
  #pragma unroll
  for (int m = 1; m < 64; m <<= 1) sm += __shfl_xor(sm, m);
  if ((t & 63) == 0) rsum[t >> 6] = sm;
  __syncthreads();
  sm = rsum[0] + rsum[1] + rsum[2] + rsum[3];
  const float inv = 1.0f / sm;
  float4 o; o.x = e0 * inv; o.y = e1 * inv; o.z = e2 * inv; o.w = e3 * inv;
  *(float4*)(sc + b * NS + t * 4) = o;
}

// ---------------- context[b,e] = sum_s w[b,s] * enc[b,s,e] ----------------
template <int CONV>
__global__ __launch_bounds__(256) void k_ctx(const void* __restrict__ encsrc,
                                             const float* __restrict__ wgt,
                                             float* __restrict__ ctx) {
  const int b = blockIdx.x >> 4, scn = blockIdx.x & 15;   // 16 s-chunks of 64
  const int t = threadIdx.x;                              // 4 e's per thread
  float a0 = 0.f, a1 = 0.f, a2 = 0.f, a3 = 0.f;
  for (int s = scn * 64; s < scn * 64 + 64; ++s) {
    const float wv = wgt[b * NS + s];
    const size_t base = ((size_t)(b * NS + s)) * NE + t * 4;
    if constexpr (CONV) {
      float4 x = *((const float4*)((const float*)encsrc + base));
      a0 += wv * x.x; a1 += wv * x.y; a2 += wv * x.z; a3 += wv * x.w;
    } else {
      short4v hv = *(const short4v*)((const unsigned short*)encsrc + base);
      a0 += wv * bf2f((unsigned short)hv[0]);
      a1 += wv * bf2f((unsigned short)hv[1]);
      a2 += wv * bf2f((unsigned short)hv[2]);
      a3 += wv * bf2f((unsigned short)hv[3]);
    }
  }
  float* c = ctx + b * NE + t * 4;
  atomicAdd(c + 0, a0); atomicAdd(c + 1, a1);
  atomicAdd(c + 2, a2); atomicAdd(c + 3, a3);
}

// ---------------- ctx f32 -> f32 output (reference output dtype is float32) ----------------
__global__ __launch_bounds__(256) void k_out(const float* __restrict__ ctx,
                                             float* __restrict__ out) {
  const int i = blockIdx.x * 256 + threadIdx.x;   // 16384 threads x 4 floats
  float4 x = *(const float4*)(ctx + i * 4);
  *(float4*)(out + i * 4) = x;
}

extern "C" void kernel_launch(void* const* d_in, const int* in_sizes, int n_in,
                              void* d_out, int out_size, void* d_ws, size_t ws_size,
                              hipStream_t stream) {
  const float* hidden = (const float*)d_in[0];
  const float* enc    = (const float*)d_in[1];
  const float* W      = (const float*)d_in[2];
  const float* bias   = (const float*)d_in[3];
  const float* v      = (const float*)d_in[4];
  (void)in_sizes; (void)n_in; (void)out_size;

  char* ws = (char*)d_ws;
  const size_t T0 = (4ull << 20) + (128ull << 20);  // Wb + u/sc/ctx + enc_bf16
  const size_t T1 = (3ull << 20);                   // Wb + u/sc/ctx
  const int tier = (ws_size >= T0) ? 0 : ((ws_size >= T1) ? 1 : 2);

  unsigned short* Wb   = (unsigned short*)ws;
  unsigned short* encb = (unsigned short*)(ws + (4ull << 20));
  float* u_  = (tier < 2) ? (float*)(ws + (2ull << 20)) : (float*)ws;
  float* sc  = u_ + NB * NA;
  float* ctx = sc + NB * NS;

  k_u<<<512, 256, 0, stream>>>(hidden, W, bias, u_);
  k_zero<<<128, 256, 0, stream>>>((float4*)sc, (NB * NS + NB * NE) / 4);

  if (tier == 0) {
    k_conv_w<<<512, 256, 0, stream>>>(W, (short8*)Wb);
    k_conv_enc<<<2048, 256, 0, stream>>>((const float4*)enc, (short8*)encb, NB * NS * NE / 8);
    k_main8<<<2048, 512, 0, stream>>>(encb, Wb, u_, v, sc);
  } else if (tier == 1) {
    k_conv_w<<<512, 256, 0, stream>>>(W, (short8*)Wb);
    k_main_rs<1, 0><<<4096, 256, 0, stream>>>(enc, Wb, u_, v, sc);
  } else {
    k_main_rs<1, 1><<<4096, 256, 0, stream>>>(enc, W, u_, v, sc);
  }

  k_softmax<<<64, 256, 0, stream>>>(sc);
  if (tier == 0) k_ctx<0><<<1024, 256, 0, stream>>>(encb, sc, ctx);
  else           k_ctx<1><<<1024, 256, 0, stream>>>(enc, sc, ctx);
  k_out<<<64, 256, 0, stream>>>(ctx, (float*)d_out);
}

// Round 7
// 281.621 us; speedup vs baseline: 1.2168x; 1.2168x over previous
//
#include <hip/hip_runtime.h>
#include <hip/hip_bf16.h>
#include <stdint.h>

// Problem constants (Attention_21552145891894): B=64, S=1024, DEC=ENC=ATTN=1024
#define NB 64
#define NS 1024
#define NE 1024   // ENC (= K of big GEMM)
#define NA 1024   // ATTN (= N of big GEMM)
#define NF 2048   // DEC+ENC (W_attn row length)
#define LDP 144   // padded LDS row stride (fallback reg-staged kernel only)

typedef __attribute__((ext_vector_type(8))) short   short8;
typedef __attribute__((ext_vector_type(4))) short   short4v;
typedef __attribute__((ext_vector_type(4))) float   f32x4;
typedef __attribute__((ext_vector_type(8))) __bf16  bf16x8;

__device__ __forceinline__ unsigned short f2bf(float x) {
  union { float f; unsigned u; } v; v.f = x;
  unsigned r = v.u + 0x7fffu + ((v.u >> 16) & 1u);   // RNE
  return (unsigned short)(r >> 16);
}
__device__ __forceinline__ float bf2f(unsigned short h) {
  union { unsigned u; float f; } v; v.u = ((unsigned)h) << 16;
  return v.f;
}
__device__ __forceinline__ float tanh_fast(float x) {
  float e = __expf(2.0f * x);                        // overflow -> inf -> 1; underflow -> -1
  return 1.0f - __fdividef(2.0f, e + 1.0f);
}
__device__ __forceinline__ short8 pack8(float4 a, float4 b) {
  short8 h;
  h[0]=(short)f2bf(a.x); h[1]=(short)f2bf(a.y); h[2]=(short)f2bf(a.z); h[3]=(short)f2bf(a.w);
  h[4]=(short)f2bf(b.x); h[5]=(short)f2bf(b.y); h[6]=(short)f2bf(b.z); h[7]=(short)f2bf(b.w);
  return h;
}
__device__ __forceinline__ void gload_lds16(const void* g, void* l) {
  // HW: LDS dest is wave-uniform base + lane*16; size must be literal 16 (m97/m104)
  __builtin_amdgcn_global_load_lds((const __attribute__((address_space(1))) void*)g,
                                   (__attribute__((address_space(3))) void*)l, 16, 0, 0);
}

// ---------------- zero scratch (scores + ctx), deterministic each call ----------------
__global__ __launch_bounds__(256) void k_zero(float4* __restrict__ p, int n4) {
  int i = blockIdx.x * 256 + threadIdx.x;
  if (i < n4) { float4 z; z.x = z.y = z.z = z.w = 0.f; p[i] = z; }
}

// ---------------- enc f32 -> bf16 (ws) ----------------
__global__ __launch_bounds__(256) void k_conv_enc(const float4* __restrict__ src,
                                                  short8* __restrict__ dst, int n8) {
  int i = blockIdx.x * 256 + threadIdx.x;
  const int stride = gridDim.x * 256;
  for (; i < n8; i += stride) {
    float4 a = src[2 * i], b = src[2 * i + 1];
    dst[i] = pack8(a, b);
  }
}

// ---------------- W_enc (= W_attn[:,1024:2048]) f32 -> bf16 [1024][1024] ----------------
__global__ __launch_bounds__(256) void k_conv_w(const float* __restrict__ W, short8* __restrict__ dst) {
  const int id = blockIdx.x * 256 + threadIdx.x;   // 131072 total
  const int a = id >> 7, ku = id & 127;
  const float* s = W + (size_t)a * NF + 1024 + ku * 8;
  float4 x = *(const float4*)s;
  float4 y = *(const float4*)(s + 4);
  dst[id] = pack8(x, y);
}

// ---------------- u[b,a] = hidden[b] . W_attn[a,0:1024] + b_attn[a]  (fp32 exact) ----------------
__global__ __launch_bounds__(256) void k_u(const float* __restrict__ hidden,
                                           const float* __restrict__ W,
                                           const float* __restrict__ bias,
                                           float* __restrict__ u) {
  const int l = threadIdx.x & 63;
  const int w = threadIdx.x >> 6;
  const int a = (blockIdx.x >> 1) * 4 + w;         // grid 512 -> a in [0,1024)
  const int bh = blockIdx.x & 1;
  const float* wrow = W + (size_t)a * NF;          // dec half: cols 0..1023
  float4 wv[4];
  #pragma unroll
  for (int i = 0; i < 4; ++i) wv[i] = *(const float4*)(wrow + l * 4 + i * 256);
  const float ba = bias[a];
  for (int b = bh * 32; b < bh * 32 + 32; ++b) {
    const float* hrow = hidden + b * 1024;
    float s = 0.f;
    #pragma unroll
    for (int i = 0; i < 4; ++i) {
      float4 hv = *(const float4*)(hrow + l * 4 + i * 256);
      s += wv[i].x * hv.x + wv[i].y * hv.y + wv[i].z * hv.z + wv[i].w * hv.w;
    }
    #pragma unroll
    for (int m = 1; m < 64; m <<= 1) s += __shfl_xor(s, m);
    if (l == 0) u[b * NA + a] = s + ba;
  }
}

// ======== main fused GEMM (tier0): 256x256 tile, double-buffered, 1 barrier/K-tile ========
// 8 waves (2M x 4N), wave tile 128x64 (LDS intensity 42.7 FLOP/B vs 64x64's 32).
// LDS: 2 buffers x {A[256][64]bf16 32KB + B[256][64]bf16 32KB} = 128KB. Per K-tile t:
//   vmcnt(0)   -- drains tile t's 8 stages, issued a FULL tile ago (aged ~2000cy >> HBM)
//   s_barrier  -- separates tile t-1's reads of buf (t+1)&1 from tile t+1's stage writes
//   stage t+1  -- 8 x global_load_lds into the opposite buffer (overlaps this tile's MFMA)
//   compute    -- hoisted A-frags (16 ds_read), 2x{4 B ds_read + setprio + 32 MFMA}
// k-unit XOR swizzle both-sides (r5-verified, 0 conflicts). Same accumulation order as
// r5 -> expect bit-identical absmax.
__global__ __launch_bounds__(512, 2) void k_main256(const unsigned short* __restrict__ Ab,
                                                    const unsigned short* __restrict__ Bb,
                                                    const float* __restrict__ u_,
                                                    const float* __restrict__ v_,
                                                    float* __restrict__ scores) {
  __shared__ __align__(16) char smem[2 * 65536];

  const int tid = threadIdx.x;
  const int l = tid & 63;
  const int w = tid >> 6;                   // 0..7
  const int wr = w >> 2, wc = w & 3;        // 2M x 4N wave grid
  // XCD-chunked remap (bijective: 1024 = 8 xcd * 128): one rt's 4 col-tiles are
  // consecutive dispatches on one XCD -> A-panel (512KB) L2 reuse; Wb (2MB) L2-resident.
  const int d = blockIdx.x;
  const int xcd = d & 7, q = d >> 3;
  const int rt = xcd * 32 + (q >> 2);       // row tile [0,256)
  const int ct = q & 3;                     // col tile [0,4)
  const int b = rt >> 2;                    // batch (256-row tiles never straddle)
  const int lh = l >> 4, l15 = l & 15, l7 = l & 7;

  // staging: 512 threads x 16B = 64 rows/issue; lane -> row (tid>>3), k-unit (tid&7);
  // source pre-swizzled by row&7 (rule #21 involution, r5-verified)
  const int ssk = ((tid & 7) ^ ((tid >> 3) & 7)) * 8;
  const unsigned short* aS = Ab + (size_t)(rt * 256 + (tid >> 3)) * NE + ssk;
  const unsigned short* bS = Bb + (size_t)(ct * 256 + (tid >> 3)) * NE + ssk;
  const int wdst = w * 1024;                // wave-uniform LDS dest offset

  f32x4 acc[8][4] = {};

#define STAGE256(tt) do { \
    char* dst_ = smem + (((tt) & 1) << 16); \
    const unsigned short* a_ = aS + (size_t)(tt) * 64; \
    const unsigned short* b_ = bS + (size_t)(tt) * 64; \
    gload_lds16(a_,                    dst_ + wdst); \
    gload_lds16(a_ + (size_t) 64 * NE, dst_ +  64 * 128 + wdst); \
    gload_lds16(a_ + (size_t)128 * NE, dst_ + 128 * 128 + wdst); \
    gload_lds16(a_ + (size_t)192 * NE, dst_ + 192 * 128 + wdst); \
    gload_lds16(b_,                    dst_ + 32768 + wdst); \
    gload_lds16(b_ + (size_t) 64 * NE, dst_ + 32768 +  64 * 128 + wdst); \
    gload_lds16(b_ + (size_t)128 * NE, dst_ + 32768 + 128 * 128 + wdst); \
    gload_lds16(b_ + (size_t)192 * NE, dst_ + 32768 + 192 * 128 + wdst); } while (0)

  STAGE256(0);                              // prologue: tile 0 into buf 0

  for (int t = 0; t < 16; ++t) {
    asm volatile("s_waitcnt vmcnt(0)" ::: "memory");   // tile t certified (aged 1 tile)
    asm volatile("s_barrier" ::: "memory");            // buf (t+1)&1 free of readers
    if (t < 15) STAGE256(t + 1);                       // overlaps with compute below

    const char* As = smem + ((t & 1) << 16);
    const char* Bs = As + 32768;

    bf16x8 areg[8][2];
    #pragma unroll
    for (int rf = 0; rf < 8; ++rf)
      #pragma unroll
      for (int kh = 0; kh < 2; ++kh)
        areg[rf][kh] = *(const bf16x8*)(As + (wr * 128 + rf * 16 + l15) * 128
                                           + (((kh * 4 + lh) ^ l7) << 4));
    #pragma unroll
    for (int cfh = 0; cfh < 2; ++cfh) {
      bf16x8 breg[2][2];
      #pragma unroll
      for (int c2 = 0; c2 < 2; ++c2)
        #pragma unroll
        for (int kh = 0; kh < 2; ++kh)
          breg[c2][kh] = *(const bf16x8*)(Bs + (wc * 64 + (cfh * 2 + c2) * 16 + l15) * 128
                                             + (((kh * 4 + lh) ^ l7) << 4));
      __builtin_amdgcn_s_setprio(1);
      #pragma unroll
      for (int rf = 0; rf < 8; ++rf)
        #pragma unroll
        for (int c2 = 0; c2 < 2; ++c2)
          #pragma unroll
          for (int kh = 0; kh < 2; ++kh)
            acc[rf][cfh * 2 + c2] = __builtin_amdgcn_mfma_f32_16x16x32_bf16(
                areg[rf][kh], breg[c2][kh], acc[rf][cfh * 2 + c2], 0, 0, 0);
      __builtin_amdgcn_s_setprio(0);
    }
  }
#undef STAGE256

  // ---- epilogue: D frag col=l&15, row=(l>>4)*4+reg (m89-verified) ----
  const int colb = ct * 256 + wc * 64 + l15;
  float uv[4], vv[4];
  #pragma unroll
  for (int cf = 0; cf < 4; ++cf) {
    const int c = colb + cf * 16;
    uv[cf] = u_[b * NA + c];
    vv[cf] = v_[c];
  }
  #pragma unroll
  for (int rf = 0; rf < 8; ++rf) {
    #pragma unroll
    for (int reg = 0; reg < 4; ++reg) {
      float sacc = 0.f;
      #pragma unroll
      for (int cf = 0; cf < 4; ++cf)
        sacc += tanh_fast(acc[rf][cf][reg] + uv[cf]) * vv[cf];
      sacc += __shfl_xor(sacc, 1);
      sacc += __shfl_xor(sacc, 2);
      sacc += __shfl_xor(sacc, 4);
      sacc += __shfl_xor(sacc, 8);
      if (l15 == 0) {
        const int m = rt * 256 + wr * 128 + rf * 16 + lh * 4 + reg;
        atomicAdd(&scores[m], sacc);         // 16 partials per row (4 ct x 4 wc)
      }
    }
  }
}

// ======== fallback (small ws): reg-staged padded-LDS version (round-3-verified) ========
template <int ACONV, int BCONV>
__global__ __launch_bounds__(256) void k_main_rs(const void* __restrict__ Asrc,
                                                 const void* __restrict__ Bsrc,
                                                 const float* __restrict__ u_,
                                                 const float* __restrict__ v_,
                                                 float* __restrict__ scores) {
  __shared__ __align__(16) char smemf[2 * 128 * LDP];
  char* As = smemf;
  char* Bs = smemf + 128 * LDP;
  const int tid = threadIdx.x;
  const int l = tid & 63;
  const int w = tid >> 6;
  const int wr = w >> 1, wc = w & 1;
  const int d = blockIdx.x;
  const int rt = (d & 7) * 64 + (d >> 6);
  const int ct = (d >> 3) & 7;
  const int b = rt >> 3;
  const int l7 = l & 7, lh = l >> 4, l15 = l & 15;
  const int srow = w * 8 + (l >> 3);
  f32x4 acc[4][4] = {};
  for (int kt = 0; kt < 16; ++kt) {
    const int k0 = kt * 64;
    __syncthreads();
    #pragma unroll
    for (int r = 0; r < 4; ++r) {
      const int row = r * 32 + srow;
      short8 val;
      if constexpr (ACONV) {
        const float* s = (const float*)Asrc + (size_t)(rt * 128 + row) * NE + k0 + l7 * 8;
        val = pack8(*(const float4*)s, *(const float4*)(s + 4));
      } else {
        val = *(const short8*)((const unsigned short*)Asrc + (size_t)(rt * 128 + row) * NE + k0 + l7 * 8);
      }
      *(short8*)(As + row * LDP + l7 * 16) = val;
    }
    #pragma unroll
    for (int r = 0; r < 4; ++r) {
      const int row = r * 32 + srow;
      short8 val;
      if constexpr (BCONV) {
        const float* s = (const float*)Bsrc + (size_t)(ct * 128 + row) * NF + 1024 + k0 + l7 * 8;
        val = pack8(*(const float4*)s, *(const float4*)(s + 4));
      } else {
        val = *(const short8*)((const unsigned short*)Bsrc + (size_t)(ct * 128 + row) * NE + k0 + l7 * 8);
      }
      *(short8*)(Bs + row * LDP + l7 * 16) = val;
    }
    __syncthreads();
    #pragma unroll
    for (int ks = 0; ks < 2; ++ks) {
      bf16x8 af[4], bfr[4];
      const int ku = (ks * 4 + lh) * 16;
      #pragma unroll
      for (int f = 0; f < 4; ++f) {
        af[f]  = *(const bf16x8*)(As + (wr * 64 + f * 16 + l15) * LDP + ku);
        bfr[f] = *(const bf16x8*)(Bs + (wc * 64 + f * 16 + l15) * LDP + ku);
      }
      #pragma unroll
      for (int i = 0; i < 4; ++i)
        #pragma unroll
        for (int jj = 0; jj < 4; ++jj)
          acc[i][jj] = __builtin_amdgcn_mfma_f32_16x16x32_bf16(af[i], bfr[jj], acc[i][jj], 0, 0, 0);
    }
  }
  const int colb = ct * 128 + wc * 64 + l15;
  float uv[4], vv[4];
  #pragma unroll
  for (int jj = 0; jj < 4; ++jj) {
    const int c = colb + jj * 16;
    uv[jj] = u_[b * NA + c];
    vv[jj] = v_[c];
  }
  #pragma unroll
  for (int i = 0; i < 4; ++i) {
    #pragma unroll
    for (int reg = 0; reg < 4; ++reg) {
      float sacc = 0.f;
      #pragma unroll
      for (int jj = 0; jj < 4; ++jj)
        sacc += tanh_fast(acc[i][jj][reg] + uv[jj]) * vv[jj];
      sacc += __shfl_xor(sacc, 1);
      sacc += __shfl_xor(sacc, 2);
      sacc += __shfl_xor(sacc, 4);
      sacc += __shfl_xor(sacc, 8);
      if (l15 == 0) {
        const int m = rt * 128 + wr * 64 + i * 16 + lh * 4 + reg;
        atomicAdd(&scores[m], sacc);
      }
    }
  }
}

// ---------------- softmax over S per batch (in-place) ----------------
__global__ __launch_bounds__(256) void k_softmax(float* __restrict__ sc) {
  const int b = blockIdx.x, t = threadIdx.x;
  float4 x = *(float4*)(sc + b * NS + t * 4);
  float mx = fmaxf(fmaxf(x.x, x.y), fmaxf(x.z, x.w));
  #pragma unroll
  for (int m = 1; m < 64; m <<= 1) mx = fmaxf(mx, __shfl_xor(mx, m));
  __shared__ float rmax[4], rsum[4];
  if ((t & 63) == 0) rmax[t >> 6] = mx;
  __syncthreads();
  mx = fmaxf(fmaxf(rmax[0], rmax[1]), fmaxf(rmax[2], rmax[3]));
  float e0 = __expf(x.x - mx), e1 = __expf(x.y - mx);
  float e2 = __expf(x.z - mx), e3 = __expf(x.w - mx);
  float sm = e0 + e1 + e2 + e3;
  #pragma unroll
  for (int m = 1; m < 64; m <<= 1) sm += __shfl_xor(sm, m);
  if ((t & 63) == 0) rsum[t >> 6] = sm;
  __syncthreads();
  sm = rsum[0] + rsum[1] + rsum[2] + rsum[3];
  const float inv = 1.0f / sm;
  float4 o; o.x = e0 * inv; o.y = e1 * inv; o.z = e2 * inv; o.w = e3 * inv;
  *(float4*)(sc + b * NS + t * 4) = o;
}

// ---------------- context[b,e] = sum_s w[b,s] * enc[b,s,e] ----------------
template <int CONV>
__global__ __launch_bounds__(256) void k_ctx(const void* __restrict__ encsrc,
                                             const float* __restrict__ wgt,
                                             float* __restrict__ ctx) {
  const int b = blockIdx.x >> 4, scn = blockIdx.x & 15;   // 16 s-chunks of 64
  const int t = threadIdx.x;                              // 4 e's per thread
  float a0 = 0.f, a1 = 0.f, a2 = 0.f, a3 = 0.f;
  for (int s = scn * 64; s < scn * 64 + 64; ++s) {
    const float wv = wgt[b * NS + s];
    const size_t base = ((size_t)(b * NS + s)) * NE + t * 4;
    if constexpr (CONV) {
      float4 x = *((const float4*)((const float*)encsrc + base));
      a0 += wv * x.x; a1 += wv * x.y; a2 += wv * x.z; a3 += wv * x.w;
    } else {
      short4v hv = *(const short4v*)((const unsigned short*)encsrc + base);
      a0 += wv * bf2f((unsigned short)hv[0]);
      a1 += wv * bf2f((unsigned short)hv[1]);
      a2 += wv * bf2f((unsigned short)hv[2]);
      a3 += wv * bf2f((unsigned short)hv[3]);
    }
  }
  float* c = ctx + b * NE + t * 4;
  atomicAdd(c + 0, a0); atomicAdd(c + 1, a1);
  atomicAdd(c + 2, a2); atomicAdd(c + 3, a3);
}

// ---------------- ctx f32 -> f32 output (reference output dtype is float32) ----------------
__global__ __launch_bounds__(256) void k_out(const float* __restrict__ ctx,
                                             float* __restrict__ out) {
  const int i = blockIdx.x * 256 + threadIdx.x;   // 16384 threads x 4 floats
  float4 x = *(const float4*)(ctx + i * 4);
  *(float4*)(out + i * 4) = x;
}

extern "C" void kernel_launch(void* const* d_in, const int* in_sizes, int n_in,
                              void* d_out, int out_size, void* d_ws, size_t ws_size,
                              hipStream_t stream) {
  const float* hidden = (const float*)d_in[0];
  const float* enc    = (const float*)d_in[1];
  const float* W      = (const float*)d_in[2];
  const float* bias   = (const float*)d_in[3];
  const float* v      = (const float*)d_in[4];
  (void)in_sizes; (void)n_in; (void)out_size;

  char* ws = (char*)d_ws;
  const size_t T0 = (4ull << 20) + (128ull << 20);  // Wb + u/sc/ctx + enc_bf16
  const size_t T1 = (3ull << 20);                   // Wb + u/sc/ctx
  const int tier = (ws_size >= T0) ? 0 : ((ws_size >= T1) ? 1 : 2);

  unsigned short* Wb   = (unsigned short*)ws;
  unsigned short* encb = (unsigned short*)(ws + (4ull << 20));
  float* u_  = (tier < 2) ? (float*)(ws + (2ull << 20)) : (float*)ws;
  float* sc  = u_ + NB * NA;
  float* ctx = sc + NB * NS;

  k_u<<<512, 256, 0, stream>>>(hidden, W, bias, u_);
  k_zero<<<128, 256, 0, stream>>>((float4*)sc, (NB * NS + NB * NE) / 4);

  if (tier == 0) {
    k_conv_w<<<512, 256, 0, stream>>>(W, (short8*)Wb);
    k_conv_enc<<<2048, 256, 0, stream>>>((const float4*)enc, (short8*)encb, NB * NS * NE / 8);
    k_main256<<<1024, 512, 0, stream>>>(encb, Wb, u_, v, sc);
  } else if (tier == 1) {
    k_conv_w<<<512, 256, 0, stream>>>(W, (short8*)Wb);
    k_main_rs<1, 0><<<4096, 256, 0, stream>>>(enc, Wb, u_, v, sc);
  } else {
    k_main_rs<1, 1><<<4096, 256, 0, stream>>>(enc, W, u_, v, sc);
  }

  k_softmax<<<64, 256, 0, stream>>>(sc);
  if (tier == 0) k_ctx<0><<<1024, 256, 0, stream>>>(encb, sc, ctx);
  else           k_ctx<1><<<1024, 256, 0, stream>>>(enc, sc, ctx);
  k_out<<<64, 256, 0, stream>>>(ctx, (float*)d_out);
}